// Round 24
// baseline (96.365 us; speedup 1.0000x reference)
//
#include <hip/hip_runtime.h>
#include <hip/hip_bf16.h>

#define NN 50000
#define NE 1600000
#define D  128
#define NB   500            // coarse buckets (k_aggemm grid: ~2 blk/CU)
#define NPB  100            // nodes per bucket
#define RCAP 4224           // region capacity per bucket (mean 3200 + 18 sigma)
#define NBB  512            // bucket-role blocks (run len 6.1 -> line-sharing writes)
#define ECH  3125           // edges per bucket-role block (512 * 3125 = NE)
#define CASTB 1024          // cast-role blocks
#define FRONTG (NBB + CASTB + 8)
#define NGRP 7              // ceil(NPB/16) row groups per bucket
#define PSTR 132            // part[] stride: bank = (4*row+col)%32 -> 2-way max

typedef unsigned int u32;
typedef unsigned long long u64;
typedef unsigned short u16;
typedef __attribute__((ext_vector_type(8))) short short8;
typedef __attribute__((ext_vector_type(4))) float f32x4;
typedef __attribute__((ext_vector_type(2))) float f32x2;

// ws layout (bytes):
//   gcur u32[NB]        @ 0          (memset 0)
//   region u32[NB*RCAP] @ 4096       (8.45 MB)
//   xf8  fp8[(NN+1)*D]  @ 8452096    (6.4 MB)  e4m3; row NN = zeros
//   xb   bf16[NN*D]     @ 14852224   (12.8 MB)
//   Wb   bf16[2*D*D]    @ 27652224   (64 KB)   Wl|Wr
#define GCUR_OFF 0
#define REG_OFF  4096
#define XF8_OFF  8452096
#define XB_OFF   14852224
#define WB_OFF   27652224

__device__ __forceinline__ u32 pack2(float a, float b) {   // 2x f32 -> bf16 RNE
    u32 ua = __float_as_uint(a), ub = __float_as_uint(b);
    ua = (ua + 0x7FFFu + ((ua >> 16) & 1u)) >> 16;
    ub = (ub + 0x7FFFu + ((ub >> 16) & 1u)) >> 16;
    return ua | (ub << 16);
}

// ---------------------------------------------------------------------------
// Front mega-kernel: independent roles co-scheduled for overlap.
//   blocks [0, 512):        bucket sort (round 23: DIRECT global scatter —
//                           srt + Phase C deleted, one fewer barrier, 22 KB LDS)
//   blocks [512, 1536):     x -> xf8 + xb cast (bandwidth-bound)
//   blocks [1536, 1544):    W -> bf16 prep + xf8 zero row
__global__ __launch_bounds__(512) void k_front(const int* __restrict__ ei,
                                               const float* __restrict__ x,
                                               const float* __restrict__ Wl,
                                               const float* __restrict__ Wr,
                                               u32* __restrict__ gcur,
                                               u32* __restrict__ region,
                                               uint2* __restrict__ xf8,
                                               uint4* __restrict__ xb,
                                               uint4* __restrict__ Wb,
                                               u32* __restrict__ xzrow) {
    __shared__ u32 eL[ECH + 6];
    __shared__ u32 lh[512], sc[512], gb[512], lc[512];
    __shared__ u32 ps[256];

    const int bid = blockIdx.x;
    const int t = threadIdx.x;

    if (bid >= NBB + CASTB) {
        // ---- prep role: 8 blocks x 512 = 4096 W slots ----
        const int s = (bid - NBB - CASTB) * 512 + t;
        const int mat = s >> 11;
        const int j   = (s >> 4) & 127;
        const int k8  = (s & 15) * 8;
        const float* src = (mat ? Wr : Wl) + (size_t)j * 128 + k8;
        const float4 a = reinterpret_cast<const float4*>(src)[0];
        const float4 b = reinterpret_cast<const float4*>(src)[1];
        uint4 o;
        o.x = pack2(a.x, a.y); o.y = pack2(a.z, a.w);
        o.z = pack2(b.x, b.y); o.w = pack2(b.z, b.w);
        Wb[s] = o;
        if (s < 32) xzrow[s] = 0u;     // fp8 0x00 == 0.0f
        return;
    }

    if (bid >= NBB) {
        // ---- cast role ----
        const int total = NN * D / 8;  // 800000
        for (int i = (bid - NBB) * 512 + t; i < total; i += CASTB * 512) {
            const float4 a = reinterpret_cast<const float4*>(x)[2 * i];
            const float4 b = reinterpret_cast<const float4*>(x)[2 * i + 1];
            uint2 o8;
            o8.x = (u32)__builtin_amdgcn_cvt_pk_fp8_f32(a.z, a.w,
                     __builtin_amdgcn_cvt_pk_fp8_f32(a.x, a.y, 0, false), true);
            o8.y = (u32)__builtin_amdgcn_cvt_pk_fp8_f32(b.z, b.w,
                     __builtin_amdgcn_cvt_pk_fp8_f32(b.x, b.y, 0, false), true);
            xf8[i] = o8;
            uint4 ob;
            ob.x = pack2(a.x, a.y); ob.y = pack2(a.z, a.w);
            ob.z = pack2(b.x, b.y); ob.w = pack2(b.z, b.w);
            xb[i] = ob;
        }
        return;
    }

    // ---- bucket role ----
    const int lane = t & 63;
    const u64 zmask = __ballot((u32)ei[2 * lane + 1] == 0u);
    const bool is64 = (zmask == ~0ull);

    const int e0 = bid * ECH;

    lh[t] = 0u; lc[t] = 0u;
    __syncthreads();

    // Phase A: load + histogram.  Entry = (bucket<<23)|(dst_local<<16)|src.
    for (int i = t; i < ECH; i += 512) {
        const int e = e0 + i;
        int src, dst;
        if (is64) { src = ei[2 * (size_t)e]; dst = ei[2 * (size_t)(NE + e)]; }
        else      { src = ei[e];             dst = ei[NE + e]; }
        const u32 b2 = (u32)dst / NPB;
        const u32 dl = (u32)dst - b2 * NPB;
        eL[i] = (b2 << 23) | (dl << 16) | (u32)src;
        atomicAdd(&lh[b2], 1u);
    }
    __syncthreads();

    // two-level inclusive scan over 512 bins
    u32 a0 = 0u, a1 = 0u;
    if (t < 256) { a0 = lh[2 * t]; a1 = lh[2 * t + 1]; ps[t] = a0 + a1; }
    __syncthreads();
    for (int ofs = 1; ofs < 256; ofs <<= 1) {
        u32 v = 0u;
        if (t < 256 && t >= ofs) v = ps[t - ofs];
        __syncthreads();
        if (t < 256) ps[t] += v;
        __syncthreads();
    }
    if (t < 256) {
        const u32 base = ps[t] - (a0 + a1);
        sc[2 * t]     = base + a0;
        sc[2 * t + 1] = base + a0 + a1;
        if (a0) gb[2 * t]     = atomicAdd(&gcur[2 * t],     a0);
        if (a1) gb[2 * t + 1] = atomicAdd(&gcur[2 * t + 1], a1);
    }
    __syncthreads();

    // Phase B': DIRECT global scatter — run positions via LDS counter;
    // entries of one bucket land in the same contiguous run (line-shared).
    for (int i = t; i < ECH; i += 512) {
        const u32 e  = eL[i];
        const u32 b2 = e >> 23;
        const u32 lp = atomicAdd(&lc[b2], 1u);
        const u32 pos = gb[b2] + lp;
        if (pos < RCAP) region[(size_t)b2 * RCAP + pos] = e;
    }
}

// ---------------------------------------------------------------------------
// Fused aggregate + GEMM (round 23 restructure): one block (1024 thr, 16
// waves) per bucket. After the dst-sort: BALANCED gather phase (wave w owns
// rows w, w+16, ... -> ~6.25 rows each, one barrier total — removes the
// max-of-16-Poisson group-barrier inflation), means -> swizzled LDS mbuf.
// Then the MFMA phase per 16-row group: mean-half waves read mbuf, x-half
// waves load A-fragments DIRECTLY from global xb (no As staging), one
// barrier per group for the part exchange. Clamped loads + guarded stores
// handle the ragged tail (rows >= NPB discarded).
#define GLOAD(J) \
    const int  i##J = i + 2 * J + half; \
    const u32 ev##J = srt[i##J]; \
    const u32 sr##J = (i##J < s1) ? (ev##J & 0xFFFFu) : (u32)NN; \
    const u32 wv##J = xf8[(size_t)sr##J * 32 + q];

#define GACC(J) { \
    const f32x2 lo = __builtin_amdgcn_cvt_pk_f32_fp8((int)wv##J, false); \
    const f32x2 hi = __builtin_amdgcn_cvt_pk_f32_fp8((int)wv##J, true); \
    a01 += lo; a23 += hi; }

__global__ __launch_bounds__(1024, 8) void k_aggemm(const u32* __restrict__ xf8,
                                                    const u32* __restrict__ region,
                                                    const u32* __restrict__ gcur,
                                                    const uint4* __restrict__ xb,
                                                    const uint4* __restrict__ Wb,
                                                    const float* __restrict__ bl,
                                                    float* __restrict__ out) {
    __shared__ u32 srt[RCAP + 8];        // 16.9 KB dst-sorted entries (+pad)
    __shared__ u32 hist[128], segs[128], cur[128];
    __shared__ u16 mbuf[NPB * 128];      // 25.6 KB mean rows (bf16, swizzled)
    __shared__ float part[2][16][PSTR];  // 16.9 KB double-buffered K-partials

    const int t = threadIdx.x;
    const int b = blockIdx.x;

    if (t < 128) { hist[t] = 0u; cur[t] = 0u; }
    __syncthreads();

    u32 cnt = gcur[b];
    if (cnt > RCAP) cnt = RCAP;
    const u32* reg = region + (size_t)b * RCAP;

    // pass 1: histogram (coalesced global read)
    for (int i = t; i < (int)cnt; i += 1024)
        atomicAdd(&hist[(reg[i] >> 16) & 0x7Fu], 1u);
    __syncthreads();

    // inclusive scan of 128 bins
    if (t < 128) segs[t] = hist[t];
    __syncthreads();
    for (int ofs = 1; ofs < 128; ofs <<= 1) {
        u32 v = 0u;
        if (t < 128 && t >= ofs) v = segs[t - ofs];
        __syncthreads();
        if (t < 128) segs[t] += v;
        __syncthreads();
    }

    // pass 2: scatter into dst-sorted LDS order (second global read)
    for (int i = t; i < (int)cnt; i += 1024) {
        const u32 e = reg[i];
        const u32 dl = (e >> 16) & 0x7Fu;
        const u32 p = (segs[dl] - hist[dl]) + atomicAdd(&cur[dl], 1u);
        srt[p] = e;
    }
    if (t < 8) srt[cnt + t] = (u32)NN;
    __syncthreads();

    // ---- per-wave identities ----
    const int w    = t >> 6;        // wave 0..15
    const int lane = t & 63;
    const int half = lane >> 5;
    const u32 q    = (u32)(lane & 31);
    const int m16  = lane & 15;
    const int kg   = lane >> 4;     // 0..3
    const int tc   = w & 7;         // col-tile (16 cols)
    const int kh   = w >> 3;        // K-half: 0 = mean@Wl, 1 = x@Wr
    const int row0 = b * NPB;

    // ---- balanced gather: wave w owns rows w, w+16, ...; ONE barrier ----
    for (int r = w; r < NPB; r += 16) {
        const int deg = (int)hist[r];
        const int s1  = (int)segs[r];
        const int s0  = s1 - deg;

        f32x2 a01 = {0.f, 0.f}, a23 = {0.f, 0.f};
        for (int i = s0; i < s1; i += 8) {
            GLOAD(0) GLOAD(1) GLOAD(2) GLOAD(3)    // 4 independent row loads
            GACC(0) GACC(1) GACC(2) GACC(3)
        }

        const float r0 = a01.x + __shfl_xor(a01.x, 32);
        const float r1 = a01.y + __shfl_xor(a01.y, 32);
        const float r2 = a23.x + __shfl_xor(a23.x, 32);
        const float r3 = a23.y + __shfl_xor(a23.y, 32);

        if (lane < 32) {   // mean dims 4q..4q+3 -> mbuf[r], bf16, swizzled
            const float inv = deg ? 1.0f / (float)deg : 0.0f;
            uint2 o;
            o.x = pack2(r0 * inv, r1 * inv);
            o.y = pack2(r2 * inv, r3 * inv);
            const u32 byteM = ((u32)(r * 256 + q * 8)) ^ ((u32)(r & 7) << 4);
            *reinterpret_cast<uint2*>(reinterpret_cast<char*>(mbuf) + byteM) = o;
        }
    }
    __syncthreads();       // all means in mbuf

    // W fragments: 4 x short8 = 16 VGPRs, loaded once (L2-hot).
    const char* wbb = reinterpret_cast<const char*>(Wb) + kh * 32768
                    + (size_t)(tc * 16 + m16) * 256 + kg * 16;
    const short8 wf0 = *reinterpret_cast<const short8*>(wbb);
    const short8 wf1 = *reinterpret_cast<const short8*>(wbb + 64);
    const short8 wf2 = *reinterpret_cast<const short8*>(wbb + 128);
    const short8 wf3 = *reinterpret_cast<const short8*>(wbb + 192);
    const float bias = bl[tc * 16 + m16];

    // ---- MFMA phase: one barrier per 16-row group ----
    for (int g = 0; g < NGRP; ++g) {
        const int grow = g * 16 + m16;
        const int rowc = (grow < NPB) ? grow : (NPB - 1);   // clamp (discarded)

        f32x4 acc = {0.f, 0.f, 0.f, 0.f};
        if (kh == 0) {
            // mean half: A-fragments from mbuf (LDS, swizzled)
            const u32 rb = (u32)(rowc * 256) ;
            const u32 sw = ((u32)(rowc & 7) << 4);
            const short8 af0 = *reinterpret_cast<const short8*>(reinterpret_cast<const char*>(mbuf) + ((rb + (  0 + kg * 8) * 2) ^ sw));
            const short8 af1 = *reinterpret_cast<const short8*>(reinterpret_cast<const char*>(mbuf) + ((rb + ( 32 + kg * 8) * 2) ^ sw));
            const short8 af2 = *reinterpret_cast<const short8*>(reinterpret_cast<const char*>(mbuf) + ((rb + ( 64 + kg * 8) * 2) ^ sw));
            const short8 af3 = *reinterpret_cast<const short8*>(reinterpret_cast<const char*>(mbuf) + ((rb + ( 96 + kg * 8) * 2) ^ sw));
            acc = __builtin_amdgcn_mfma_f32_16x16x32_bf16(af0, wf0, acc, 0, 0, 0);
            acc = __builtin_amdgcn_mfma_f32_16x16x32_bf16(af1, wf1, acc, 0, 0, 0);
            acc = __builtin_amdgcn_mfma_f32_16x16x32_bf16(af2, wf2, acc, 0, 0, 0);
            acc = __builtin_amdgcn_mfma_f32_16x16x32_bf16(af3, wf3, acc, 0, 0, 0);
        } else {
            // x half: A-fragments directly from global xb (L2/L3-hot)
            const uint4* xrow = xb + (size_t)(row0 + rowc) * 16 + kg;
            const short8 af0 = *reinterpret_cast<const short8*>(xrow);
            const short8 af1 = *reinterpret_cast<const short8*>(xrow + 4);
            const short8 af2 = *reinterpret_cast<const short8*>(xrow + 8);
            const short8 af3 = *reinterpret_cast<const short8*>(xrow + 12);
            acc = __builtin_amdgcn_mfma_f32_16x16x32_bf16(af0, wf0, acc, 0, 0, 0);
            acc = __builtin_amdgcn_mfma_f32_16x16x32_bf16(af1, wf1, acc, 0, 0, 0);
            acc = __builtin_amdgcn_mfma_f32_16x16x32_bf16(af2, wf2, acc, 0, 0, 0);
            acc = __builtin_amdgcn_mfma_f32_16x16x32_bf16(af3, wf3, acc, 0, 0, 0);
            #pragma unroll
            for (int i = 0; i < 4; i++)
                part[g & 1][kg * 4 + i][tc * 16 + m16] = acc[i];
        }
        __syncthreads();   // partials ready

        if (kh == 0) {     // combine + bias + relu + guarded store
            #pragma unroll
            for (int i = 0; i < 4; i++) {
                const int gr = g * 16 + kg * 4 + i;
                if (gr < NPB) {
                    const float s = acc[i] + part[g & 1][kg * 4 + i][tc * 16 + m16] + bias;
                    out[(size_t)(row0 + gr) * D + tc * 16 + m16] = fmaxf(s, 0.f);
                }
            }
        }
    }
}

// ---------------------------------------------------------------------------
extern "C" void kernel_launch(void* const* d_in, const int* in_sizes, int n_in,
                              void* d_out, int out_size, void* d_ws, size_t ws_size,
                              hipStream_t stream) {
    const float* x  = (const float*)d_in[0];
    const int*   ei = (const int*)  d_in[1];
    const float* Wl = (const float*)d_in[2];
    const float* bl = (const float*)d_in[3];
    const float* Wr = (const float*)d_in[4];

    char* ws = (char*)d_ws;
    u32*   gcur   = (u32*)(ws + GCUR_OFF);
    u32*   region = (u32*)(ws + REG_OFF);
    u32*   xf8    = (u32*)(ws + XF8_OFF);
    uint4* xb     = (uint4*)(ws + XB_OFF);
    uint4* Wb     = (uint4*)(ws + WB_OFF);
    float* out    = (float*)d_out;

    hipMemsetAsync(ws, 0, 4096, stream);    // gcur
    k_front <<<FRONTG, 512, 0, stream>>>(ei, x, Wl, Wr, gcur, region,
                                         (uint2*)xf8, xb, Wb, xf8 + (size_t)NN * 32);
    k_aggemm<<<NB, 1024, 0, stream>>>(xf8, region, gcur, xb, Wb, bl, out);
}

// Round 25
// 82.743 us; speedup vs baseline: 1.1646x; 1.1646x over previous
//
#include <hip/hip_runtime.h>
#include <hip/hip_bf16.h>

#define NN 50000
#define NE 1600000
#define D  128
#define NB   500            // coarse buckets (k_aggemm grid: ~2 blk/CU)
#define NPB  100            // nodes per bucket
#define RCAP 4224           // region capacity per bucket (mean 3200 + 18 sigma)
#define NBB  512            // bucket-role blocks (run len 6.1 -> coalesced Phase C)
#define ECH  3125           // edges per bucket-role block (512 * 3125 = NE)
#define CASTB 1024          // cast-role blocks
#define FRONTG (NBB + CASTB + 8)
#define NGRP 7              // ceil(NPB/16) row groups per bucket
#define PSTR 132            // part[] stride: bank = (4*row+col)%32 -> 2-way max

typedef unsigned int u32;
typedef unsigned long long u64;
typedef unsigned short u16;
typedef __attribute__((ext_vector_type(8))) short short8;
typedef __attribute__((ext_vector_type(4))) float f32x4;
typedef __attribute__((ext_vector_type(2))) float f32x2;

// ws layout (bytes):
//   gcur u32[NB]        @ 0          (memset 0)
//   region u32[NB*RCAP] @ 4096       (8.45 MB)
//   xf8  fp8[(NN+1)*D]  @ 8452096    (6.4 MB)  e4m3; row NN = zeros
//   xb   bf16[NN*D]     @ 14852224   (12.8 MB)
//   Wb   bf16[2*D*D]    @ 27652224   (64 KB)   Wl|Wr
#define GCUR_OFF 0
#define REG_OFF  4096
#define XF8_OFF  8452096
#define XB_OFF   14852224
#define WB_OFF   27652224

__device__ __forceinline__ u32 pack2(float a, float b) {   // 2x f32 -> bf16 RNE
    u32 ua = __float_as_uint(a), ub = __float_as_uint(b);
    ua = (ua + 0x7FFFu + ((ua >> 16) & 1u)) >> 16;
    ub = (ub + 0x7FFFu + ((ub >> 16) & 1u)) >> 16;
    return ua | (ub << 16);
}

// ---------------------------------------------------------------------------
// Front mega-kernel: independent roles co-scheduled for overlap (round 23
// proven config: Phase B LDS grouping + Phase C flat coalesced copy).
__global__ __launch_bounds__(512) void k_front(const int* __restrict__ ei,
                                               const float* __restrict__ x,
                                               const float* __restrict__ Wl,
                                               const float* __restrict__ Wr,
                                               u32* __restrict__ gcur,
                                               u32* __restrict__ region,
                                               uint2* __restrict__ xf8,
                                               uint4* __restrict__ xb,
                                               uint4* __restrict__ Wb,
                                               u32* __restrict__ xzrow) {
    __shared__ u32 eL[ECH + 6];
    __shared__ u32 srt[ECH + 6];
    __shared__ u32 lh[512], sc[512], gb[512], lc[512];
    __shared__ u32 ps[256];

    const int bid = blockIdx.x;
    const int t = threadIdx.x;

    if (bid >= NBB + CASTB) {
        // ---- prep role: 8 blocks x 512 = 4096 W slots ----
        const int s = (bid - NBB - CASTB) * 512 + t;
        const int mat = s >> 11;
        const int j   = (s >> 4) & 127;
        const int k8  = (s & 15) * 8;
        const float* src = (mat ? Wr : Wl) + (size_t)j * 128 + k8;
        const float4 a = reinterpret_cast<const float4*>(src)[0];
        const float4 b = reinterpret_cast<const float4*>(src)[1];
        uint4 o;
        o.x = pack2(a.x, a.y); o.y = pack2(a.z, a.w);
        o.z = pack2(b.x, b.y); o.w = pack2(b.z, b.w);
        Wb[s] = o;
        if (s < 32) xzrow[s] = 0u;     // fp8 0x00 == 0.0f
        return;
    }

    if (bid >= NBB) {
        // ---- cast role ----
        const int total = NN * D / 8;  // 800000
        for (int i = (bid - NBB) * 512 + t; i < total; i += CASTB * 512) {
            const float4 a = reinterpret_cast<const float4*>(x)[2 * i];
            const float4 b = reinterpret_cast<const float4*>(x)[2 * i + 1];
            uint2 o8;
            o8.x = (u32)__builtin_amdgcn_cvt_pk_fp8_f32(a.z, a.w,
                     __builtin_amdgcn_cvt_pk_fp8_f32(a.x, a.y, 0, false), true);
            o8.y = (u32)__builtin_amdgcn_cvt_pk_fp8_f32(b.z, b.w,
                     __builtin_amdgcn_cvt_pk_fp8_f32(b.x, b.y, 0, false), true);
            xf8[i] = o8;
            uint4 ob;
            ob.x = pack2(a.x, a.y); ob.y = pack2(a.z, a.w);
            ob.z = pack2(b.x, b.y); ob.w = pack2(b.z, b.w);
            xb[i] = ob;
        }
        return;
    }

    // ---- bucket role ----
    const int lane = t & 63;
    const u64 zmask = __ballot((u32)ei[2 * lane + 1] == 0u);
    const bool is64 = (zmask == ~0ull);

    const int e0 = bid * ECH;

    lh[t] = 0u; lc[t] = 0u;
    __syncthreads();

    // Phase A: load + histogram.  Entry = (bucket<<23)|(dst_local<<16)|src.
    for (int i = t; i < ECH; i += 512) {
        const int e = e0 + i;
        int src, dst;
        if (is64) { src = ei[2 * (size_t)e]; dst = ei[2 * (size_t)(NE + e)]; }
        else      { src = ei[e];             dst = ei[NE + e]; }
        const u32 b2 = (u32)dst / NPB;
        const u32 dl = (u32)dst - b2 * NPB;
        eL[i] = (b2 << 23) | (dl << 16) | (u32)src;
        atomicAdd(&lh[b2], 1u);
    }
    __syncthreads();

    // two-level inclusive scan over 512 bins
    u32 a0 = 0u, a1 = 0u;
    if (t < 256) { a0 = lh[2 * t]; a1 = lh[2 * t + 1]; ps[t] = a0 + a1; }
    __syncthreads();
    for (int ofs = 1; ofs < 256; ofs <<= 1) {
        u32 v = 0u;
        if (t < 256 && t >= ofs) v = ps[t - ofs];
        __syncthreads();
        if (t < 256) ps[t] += v;
        __syncthreads();
    }
    if (t < 256) {
        const u32 base = ps[t] - (a0 + a1);
        sc[2 * t]     = base + a0;
        sc[2 * t + 1] = base + a0 + a1;
        if (a0) gb[2 * t]     = atomicAdd(&gcur[2 * t],     a0);
        if (a1) gb[2 * t + 1] = atomicAdd(&gcur[2 * t + 1], a1);
    }
    __syncthreads();

    // Phase B: group by bucket in LDS
    for (int i = t; i < ECH; i += 512) {
        const u32 e = eL[i];
        const u32 b2 = e >> 23;
        const u32 lp = atomicAdd(&lc[b2], 1u);
        srt[(sc[b2] - lh[b2]) + lp] = e;
    }
    __syncthreads();

    // Phase C: flat entry-parallel copy (run-coalesced)
    for (int i = t; i < ECH; i += 512) {
        const u32 e    = srt[i];
        const u32 b2   = e >> 23;
        const u32 run0 = sc[b2] - lh[b2];
        const u32 pos  = gb[b2] + ((u32)i - run0);
        if (pos < RCAP) region[(size_t)b2 * RCAP + pos] = e;
    }
}

// ---------------------------------------------------------------------------
// Fused aggregate + GEMM: one block (1024 thr, 16 waves) per bucket.
// Round 24 delta vs the 83.9 µs measurement: gather unrolled 8 -> 16
// edges/iter (8 row loads in flight per lane). Everything else identical.
#define GLOAD(J) \
    const int  i##J = i + 2 * J + half; \
    const u32 ev##J = srt[i##J]; \
    const u32 sr##J = (i##J < s1) ? (ev##J & 0xFFFFu) : (u32)NN; \
    const u32 wv##J = xf8[(size_t)sr##J * 32 + q];

#define GACC(J) { \
    const f32x2 lo = __builtin_amdgcn_cvt_pk_f32_fp8((int)wv##J, false); \
    const f32x2 hi = __builtin_amdgcn_cvt_pk_f32_fp8((int)wv##J, true); \
    a01 += lo; a23 += hi; }

__global__ __launch_bounds__(1024, 8) void k_aggemm(const u32* __restrict__ xf8,
                                                    const u32* __restrict__ region,
                                                    const u32* __restrict__ gcur,
                                                    const uint4* __restrict__ xb,
                                                    const uint4* __restrict__ Wb,
                                                    const float* __restrict__ bl,
                                                    float* __restrict__ out) {
    __shared__ u32 ent[RCAP];            // 16.9 KB staged entries (1 global pass)
    __shared__ u32 srt[RCAP + 16];       // 16.9 KB dst-sorted entries (+pad 16)
    __shared__ u32 hist[128], segs[128], cur[128];
    __shared__ u16 As[16 * 256];         // 8 KB  [row-in-group][K=256] swizzled
    __shared__ float part[2][16][PSTR];  // 16.9 KB double-buffered K-partials

    const int t = threadIdx.x;
    const int b = blockIdx.x;

    if (t < 128) { hist[t] = 0u; cur[t] = 0u; }
    __syncthreads();

    u32 cnt = gcur[b];
    if (cnt > RCAP) cnt = RCAP;
    const u32* reg = region + (size_t)b * RCAP;

    // pass 1: stage + histogram (single global read)
    for (int i = t; i < (int)cnt; i += 1024) {
        const u32 e = reg[i];
        ent[i] = e;
        atomicAdd(&hist[(e >> 16) & 0x7Fu], 1u);
    }
    __syncthreads();

    // inclusive scan of 128 bins
    if (t < 128) segs[t] = hist[t];
    __syncthreads();
    for (int ofs = 1; ofs < 128; ofs <<= 1) {
        u32 v = 0u;
        if (t < 128 && t >= ofs) v = segs[t - ofs];
        __syncthreads();
        if (t < 128) segs[t] += v;
        __syncthreads();
    }

    // pass 2: scatter into dst-sorted LDS order (from ent, no global read)
    for (int i = t; i < (int)cnt; i += 1024) {
        const u32 e = ent[i];
        const u32 dl = (e >> 16) & 0x7Fu;
        const u32 p = (segs[dl] - hist[dl]) + atomicAdd(&cur[dl], 1u);
        srt[p] = e;
    }
    if (t < 16) srt[cnt + t] = (u32)NN;  // pad (reads beyond s1 select-guarded)
    __syncthreads();

    // ---- per-wave identities ----
    const int w    = t >> 6;        // wave 0..15
    const int lane = t & 63;
    const int half = lane >> 5;
    const u32 q    = (u32)(lane & 31);
    const int m16  = lane & 15;
    const int kg   = lane >> 4;     // 0..3
    const int tc   = w & 7;         // col-tile (16 cols)
    const int kh   = w >> 3;        // K-half: 0 = mean@Wl, 1 = x@Wr
    const int row0 = b * NPB;

    // W fragments: 4 x short8 = 16 VGPRs, loaded once (L2-hot).
    const char* wbb = reinterpret_cast<const char*>(Wb) + kh * 32768
                    + (size_t)(tc * 16 + m16) * 256 + kg * 16;
    const short8 wf0 = *reinterpret_cast<const short8*>(wbb);
    const short8 wf1 = *reinterpret_cast<const short8*>(wbb + 64);
    const short8 wf2 = *reinterpret_cast<const short8*>(wbb + 128);
    const short8 wf3 = *reinterpret_cast<const short8*>(wbb + 192);
    const float bias = bl[tc * 16 + m16];

    // staging ids for the x-half (threads 0..255)
    const int sm   = t >> 4;        // row-in-group 0..15 (t<256)
    const int slot = t & 15;
    const u32 byteX = ((u32)(sm * 512 + (128 + slot * 8) * 2)) ^ ((u32)(sm & 7) << 4);

    for (int g = 0; g < NGRP; ++g) {
        // ---- stage x-half rows (issue early; independent of gather) ----
        if (t < 256) {
            const int grow = g * 16 + sm;
            uint4 ox = {0u, 0u, 0u, 0u};
            if (grow < NPB) ox = xb[(size_t)(row0 + grow) * 16 + slot];
            *reinterpret_cast<uint4*>(reinterpret_cast<char*>(As) + byteX) = ox;
        }

        // ---- gather this wave's row: r = 16g + w  (16 edges/iter) ----
        const int r = g * 16 + w;
        if (r < NPB) {
            const int deg = (int)hist[r];
            const int s1  = (int)segs[r];
            const int s0  = s1 - deg;

            f32x2 a01 = {0.f, 0.f}, a23 = {0.f, 0.f};
            for (int i = s0; i < s1; i += 16) {
                GLOAD(0) GLOAD(1) GLOAD(2) GLOAD(3)
                GLOAD(4) GLOAD(5) GLOAD(6) GLOAD(7)   // 8 loads in flight
                GACC(0) GACC(1) GACC(2) GACC(3)
                GACC(4) GACC(5) GACC(6) GACC(7)
            }

            const float r0 = a01.x + __shfl_xor(a01.x, 32);
            const float r1 = a01.y + __shfl_xor(a01.y, 32);
            const float r2 = a23.x + __shfl_xor(a23.x, 32);
            const float r3 = a23.y + __shfl_xor(a23.y, 32);

            if (lane < 32) {   // mean dims 4q..4q+3 -> As[w][4q..], bf16
                const float inv = deg ? 1.0f / (float)deg : 0.0f;
                uint2 o;
                o.x = pack2(r0 * inv, r1 * inv);
                o.y = pack2(r2 * inv, r3 * inv);
                const u32 byteM = ((u32)(w * 512 + q * 8)) ^ ((u32)(w & 7) << 4);
                *reinterpret_cast<uint2*>(reinterpret_cast<char*>(As) + byteM) = o;
            }
        }
        __syncthreads();   // As (mean + x halves) ready

        // ---- MFMA: this wave's col-tile x its K-half (4 x K32 steps) ----
        f32x4 acc = {0.f, 0.f, 0.f, 0.f};
        {
            const int kbase = kh * 128;
            const u32 ab0 = ((u32)(m16 * 512 + (kbase +  0 + kg * 8) * 2)) ^ ((u32)(m16 & 7) << 4);
            const u32 ab1 = ((u32)(m16 * 512 + (kbase + 32 + kg * 8) * 2)) ^ ((u32)(m16 & 7) << 4);
            const u32 ab2 = ((u32)(m16 * 512 + (kbase + 64 + kg * 8) * 2)) ^ ((u32)(m16 & 7) << 4);
            const u32 ab3 = ((u32)(m16 * 512 + (kbase + 96 + kg * 8) * 2)) ^ ((u32)(m16 & 7) << 4);
            const short8 af0 = *reinterpret_cast<const short8*>(reinterpret_cast<const char*>(As) + ab0);
            const short8 af1 = *reinterpret_cast<const short8*>(reinterpret_cast<const char*>(As) + ab1);
            const short8 af2 = *reinterpret_cast<const short8*>(reinterpret_cast<const char*>(As) + ab2);
            const short8 af3 = *reinterpret_cast<const short8*>(reinterpret_cast<const char*>(As) + ab3);
            acc = __builtin_amdgcn_mfma_f32_16x16x32_bf16(af0, wf0, acc, 0, 0, 0);
            acc = __builtin_amdgcn_mfma_f32_16x16x32_bf16(af1, wf1, acc, 0, 0, 0);
            acc = __builtin_amdgcn_mfma_f32_16x16x32_bf16(af2, wf2, acc, 0, 0, 0);
            acc = __builtin_amdgcn_mfma_f32_16x16x32_bf16(af3, wf3, acc, 0, 0, 0);
        }

        if (kh == 1) {     // upper K-half -> partial buffer
            #pragma unroll
            for (int i = 0; i < 4; i++)
                part[g & 1][kg * 4 + i][tc * 16 + m16] = acc[i];
        }
        __syncthreads();   // partials ready; As reads done

        if (kh == 0) {     // combine + bias + relu + guarded store
            #pragma unroll
            for (int i = 0; i < 4; i++) {
                const int grow = g * 16 + kg * 4 + i;
                if (grow < NPB) {
                    const float s = acc[i] + part[g & 1][kg * 4 + i][tc * 16 + m16] + bias;
                    out[(size_t)(row0 + grow) * D + tc * 16 + m16] = fmaxf(s, 0.f);
                }
            }
        }
    }
}

// ---------------------------------------------------------------------------
extern "C" void kernel_launch(void* const* d_in, const int* in_sizes, int n_in,
                              void* d_out, int out_size, void* d_ws, size_t ws_size,
                              hipStream_t stream) {
    const float* x  = (const float*)d_in[0];
    const int*   ei = (const int*)  d_in[1];
    const float* Wl = (const float*)d_in[2];
    const float* bl = (const float*)d_in[3];
    const float* Wr = (const float*)d_in[4];

    char* ws = (char*)d_ws;
    u32*   gcur   = (u32*)(ws + GCUR_OFF);
    u32*   region = (u32*)(ws + REG_OFF);
    u32*   xf8    = (u32*)(ws + XF8_OFF);
    uint4* xb     = (uint4*)(ws + XB_OFF);
    uint4* Wb     = (uint4*)(ws + WB_OFF);
    float* out    = (float*)d_out;

    hipMemsetAsync(ws, 0, 4096, stream);    // gcur
    k_front <<<FRONTG, 512, 0, stream>>>(ei, x, Wl, Wr, gcur, region,
                                         (uint2*)xf8, xb, Wb, xf8 + (size_t)NN * 32);
    k_aggemm<<<NB, 1024, 0, stream>>>(xf8, region, gcur, xb, Wb, bl, out);
}

// Round 26
// 72.536 us; speedup vs baseline: 1.3285x; 1.1407x over previous
//
#include <hip/hip_runtime.h>
#include <hip/hip_bf16.h>

#define NN 50000
#define NE 1600000
#define D  128
#define NB   500            // coarse buckets (k_aggemm grid: ~2 blk/CU = 32 waves max)
#define NPB  100            // nodes per bucket
#define RCAP 4224           // region capacity per bucket (mean 3200 + 18 sigma)
#define NBB  512            // bucket-role blocks (run len 6.1 -> coalesced Phase C)
#define ECH  3125           // edges per bucket-role block (512 * 3125 = NE)
#define CASTB 1024          // cast-role blocks
#define FRONTG (NBB + CASTB + 8)
#define NGRP 7              // ceil(NPB/16) row groups per bucket
#define PSTR 132            // part[] stride: bank = (4*row+col)%32 -> 2-way max

typedef unsigned int u32;
typedef unsigned long long u64;
typedef unsigned short u16;
typedef __attribute__((ext_vector_type(8))) short short8;
typedef __attribute__((ext_vector_type(4))) float f32x4;
typedef __attribute__((ext_vector_type(2))) float f32x2;

// ws layout (bytes):
//   gcur u32[NB]        @ 0          (memset 0)
//   region u32[NB*RCAP] @ 4096       (8.45 MB)
//   xf8  fp8[(NN+1)*D]  @ 8452096    (6.4 MB)  e4m3; row NN = zeros
//   Wb   bf16[2*D*D]    @ 14852224   (64 KB)   Wl|Wr
#define GCUR_OFF 0
#define REG_OFF  4096
#define XF8_OFF  8452096
#define WB_OFF   14852224

__device__ __forceinline__ u32 pack2(float a, float b) {   // 2x f32 -> bf16 RNE
    u32 ua = __float_as_uint(a), ub = __float_as_uint(b);
    ua = (ua + 0x7FFFu + ((ua >> 16) & 1u)) >> 16;
    ub = (ub + 0x7FFFu + ((ub >> 16) & 1u)) >> 16;
    return ua | (ub << 16);
}

// ---------------------------------------------------------------------------
// Front mega-kernel: independent roles co-scheduled for overlap.
//   blocks [0, 512):        bucket sort (round 25: wave-shfl scan, 2 barriers
//                           instead of 16; Phase B LDS grouping + Phase C copy)
//   blocks [512, 1536):     x -> xf8 cast only (round 25: xb dropped)
//   blocks [1536, 1544):    W -> bf16 prep + xf8 zero row
__global__ __launch_bounds__(512) void k_front(const int* __restrict__ ei,
                                               const float* __restrict__ x,
                                               const float* __restrict__ Wl,
                                               const float* __restrict__ Wr,
                                               u32* __restrict__ gcur,
                                               u32* __restrict__ region,
                                               uint2* __restrict__ xf8,
                                               uint4* __restrict__ Wb,
                                               u32* __restrict__ xzrow) {
    __shared__ u32 eL[ECH + 6];
    __shared__ u32 srt[ECH + 6];
    __shared__ u32 lh[512], sc[512], gb[512], lc[512];
    __shared__ u32 wsum[8];

    const int bid = blockIdx.x;
    const int t = threadIdx.x;

    if (bid >= NBB + CASTB) {
        // ---- prep role: 8 blocks x 512 = 4096 W slots ----
        const int s = (bid - NBB - CASTB) * 512 + t;
        const int mat = s >> 11;
        const int j   = (s >> 4) & 127;
        const int k8  = (s & 15) * 8;
        const float* src = (mat ? Wr : Wl) + (size_t)j * 128 + k8;
        const float4 a = reinterpret_cast<const float4*>(src)[0];
        const float4 b = reinterpret_cast<const float4*>(src)[1];
        uint4 o;
        o.x = pack2(a.x, a.y); o.y = pack2(a.z, a.w);
        o.z = pack2(b.x, b.y); o.w = pack2(b.z, b.w);
        Wb[s] = o;
        if (s < 32) xzrow[s] = 0u;     // fp8 0x00 == 0.0f
        return;
    }

    if (bid >= NBB) {
        // ---- cast role: x (f32) -> xf8 (fp8) only ----
        const int total = NN * D / 8;  // 800000
        for (int i = (bid - NBB) * 512 + t; i < total; i += CASTB * 512) {
            const float4 a = reinterpret_cast<const float4*>(x)[2 * i];
            const float4 b = reinterpret_cast<const float4*>(x)[2 * i + 1];
            uint2 o8;
            o8.x = (u32)__builtin_amdgcn_cvt_pk_fp8_f32(a.z, a.w,
                     __builtin_amdgcn_cvt_pk_fp8_f32(a.x, a.y, 0, false), true);
            o8.y = (u32)__builtin_amdgcn_cvt_pk_fp8_f32(b.z, b.w,
                     __builtin_amdgcn_cvt_pk_fp8_f32(b.x, b.y, 0, false), true);
            xf8[i] = o8;
        }
        return;
    }

    // ---- bucket role ----
    const int lane = t & 63;
    const u64 zmask = __ballot((u32)ei[2 * lane + 1] == 0u);
    const bool is64 = (zmask == ~0ull);

    const int e0 = bid * ECH;

    lh[t] = 0u; lc[t] = 0u;
    __syncthreads();

    // Phase A: load + histogram.  Entry = (bucket<<23)|(dst_local<<16)|src.
    for (int i = t; i < ECH; i += 512) {
        const int e = e0 + i;
        int src, dst;
        if (is64) { src = ei[2 * (size_t)e]; dst = ei[2 * (size_t)(NE + e)]; }
        else      { src = ei[e];             dst = ei[NE + e]; }
        const u32 b2 = (u32)dst / NPB;
        const u32 dl = (u32)dst - b2 * NPB;
        eL[i] = (b2 << 23) | (dl << 16) | (u32)src;
        atomicAdd(&lh[b2], 1u);
    }
    __syncthreads();

    // wave-shfl inclusive scan over 512 bins (2 barriers total)
    const u32 orig = lh[t];
    u32 v = orig;
    #pragma unroll
    for (int ofs = 1; ofs < 64; ofs <<= 1) {
        const u32 n = __shfl_up(v, ofs, 64);
        if (lane >= ofs) v += n;
    }
    if (lane == 63) wsum[t >> 6] = v;
    __syncthreads();
    u32 base = 0;
    #pragma unroll
    for (int ww = 0; ww < 8; ww++) base += (ww < (t >> 6)) ? wsum[ww] : 0u;
    v += base;
    sc[t] = v;                           // inclusive scan
    if (orig) gb[t] = atomicAdd(&gcur[t], orig);
    __syncthreads();

    // Phase B: group by bucket in LDS
    for (int i = t; i < ECH; i += 512) {
        const u32 e = eL[i];
        const u32 b2 = e >> 23;
        const u32 lp = atomicAdd(&lc[b2], 1u);
        srt[(sc[b2] - lh[b2]) + lp] = e;
    }
    __syncthreads();

    // Phase C: flat entry-parallel copy (run-coalesced)
    for (int i = t; i < ECH; i += 512) {
        const u32 e    = srt[i];
        const u32 b2   = e >> 23;
        const u32 run0 = sc[b2] - lh[b2];
        const u32 pos  = gb[b2] + ((u32)i - run0);
        if (pos < RCAP) region[(size_t)b2 * RCAP + pos] = e;
    }
}

// ---------------------------------------------------------------------------
// Fused aggregate + GEMM: one block (1024 thr, 16 waves) per bucket.
// Round 25 delta: x-half A-fragments staged directly from f32 x (xb deleted);
// gather loop identical to the 82.7 µs measurement.
#define GLOAD(J) \
    const int  i##J = i + 2 * J + half; \
    const u32 ev##J = srt[i##J]; \
    const u32 sr##J = (i##J < s1) ? (ev##J & 0xFFFFu) : (u32)NN; \
    const u32 wv##J = xf8[(size_t)sr##J * 32 + q];

#define GACC(J) { \
    const f32x2 lo = __builtin_amdgcn_cvt_pk_f32_fp8((int)wv##J, false); \
    const f32x2 hi = __builtin_amdgcn_cvt_pk_f32_fp8((int)wv##J, true); \
    a01 += lo; a23 += hi; }

__global__ __launch_bounds__(1024, 8) void k_aggemm(const u32* __restrict__ xf8,
                                                    const u32* __restrict__ region,
                                                    const u32* __restrict__ gcur,
                                                    const float* __restrict__ xf,
                                                    const uint4* __restrict__ Wb,
                                                    const float* __restrict__ bl,
                                                    float* __restrict__ out) {
    __shared__ u32 ent[RCAP];            // 16.9 KB staged entries (1 global pass)
    __shared__ u32 srt[RCAP + 16];       // 16.9 KB dst-sorted entries (+pad 16)
    __shared__ u32 hist[128], segs[128], cur[128];
    __shared__ u16 As[16 * 256];         // 8 KB  [row-in-group][K=256] swizzled
    __shared__ float part[2][16][PSTR];  // 16.9 KB double-buffered K-partials

    const int t = threadIdx.x;
    const int b = blockIdx.x;

    if (t < 128) { hist[t] = 0u; cur[t] = 0u; }
    __syncthreads();

    u32 cnt = gcur[b];
    if (cnt > RCAP) cnt = RCAP;
    const u32* reg = region + (size_t)b * RCAP;

    // pass 1: stage + histogram (single global read)
    for (int i = t; i < (int)cnt; i += 1024) {
        const u32 e = reg[i];
        ent[i] = e;
        atomicAdd(&hist[(e >> 16) & 0x7Fu], 1u);
    }
    __syncthreads();

    // inclusive scan of 128 bins
    if (t < 128) segs[t] = hist[t];
    __syncthreads();
    for (int ofs = 1; ofs < 128; ofs <<= 1) {
        u32 v = 0u;
        if (t < 128 && t >= ofs) v = segs[t - ofs];
        __syncthreads();
        if (t < 128) segs[t] += v;
        __syncthreads();
    }

    // pass 2: scatter into dst-sorted LDS order (from ent, no global read)
    for (int i = t; i < (int)cnt; i += 1024) {
        const u32 e = ent[i];
        const u32 dl = (e >> 16) & 0x7Fu;
        const u32 p = (segs[dl] - hist[dl]) + atomicAdd(&cur[dl], 1u);
        srt[p] = e;
    }
    if (t < 16) srt[cnt + t] = (u32)NN;  // pad (reads beyond s1 select-guarded)
    __syncthreads();

    // ---- per-wave identities ----
    const int w    = t >> 6;        // wave 0..15
    const int lane = t & 63;
    const int half = lane >> 5;
    const u32 q    = (u32)(lane & 31);
    const int m16  = lane & 15;
    const int kg   = lane >> 4;     // 0..3
    const int tc   = w & 7;         // col-tile (16 cols)
    const int kh   = w >> 3;        // K-half: 0 = mean@Wl, 1 = x@Wr
    const int row0 = b * NPB;

    // W fragments: 4 x short8 = 16 VGPRs, loaded once (L2-hot).
    const char* wbb = reinterpret_cast<const char*>(Wb) + kh * 32768
                    + (size_t)(tc * 16 + m16) * 256 + kg * 16;
    const short8 wf0 = *reinterpret_cast<const short8*>(wbb);
    const short8 wf1 = *reinterpret_cast<const short8*>(wbb + 64);
    const short8 wf2 = *reinterpret_cast<const short8*>(wbb + 128);
    const short8 wf3 = *reinterpret_cast<const short8*>(wbb + 192);
    const float bias = bl[tc * 16 + m16];

    // staging ids for the x-half (threads 0..255)
    const int sm   = t >> 4;        // row-in-group 0..15 (t<256)
    const int slot = t & 15;
    const u32 byteX = ((u32)(sm * 512 + (128 + slot * 8) * 2)) ^ ((u32)(sm & 7) << 4);

    for (int g = 0; g < NGRP; ++g) {
        // ---- stage x-half rows from f32 x (issue early; hidden by gather) ----
        if (t < 256) {
            const int grow = g * 16 + sm;
            uint4 o = {0u, 0u, 0u, 0u};
            if (grow < NPB) {
                const float* srcx = xf + (size_t)(row0 + grow) * D + slot * 8;
                const float4 a = reinterpret_cast<const float4*>(srcx)[0];
                const float4 bb = reinterpret_cast<const float4*>(srcx)[1];
                o.x = pack2(a.x, a.y);  o.y = pack2(a.z, a.w);
                o.z = pack2(bb.x, bb.y); o.w = pack2(bb.z, bb.w);
            }
            *reinterpret_cast<uint4*>(reinterpret_cast<char*>(As) + byteX) = o;
        }

        // ---- gather this wave's row: r = 16g + w  (16 edges/iter) ----
        const int r = g * 16 + w;
        if (r < NPB) {
            const int deg = (int)hist[r];
            const int s1  = (int)segs[r];
            const int s0  = s1 - deg;

            f32x2 a01 = {0.f, 0.f}, a23 = {0.f, 0.f};
            for (int i = s0; i < s1; i += 16) {
                GLOAD(0) GLOAD(1) GLOAD(2) GLOAD(3)
                GLOAD(4) GLOAD(5) GLOAD(6) GLOAD(7)   // 8 loads in flight
                GACC(0) GACC(1) GACC(2) GACC(3)
                GACC(4) GACC(5) GACC(6) GACC(7)
            }

            const float r0 = a01.x + __shfl_xor(a01.x, 32);
            const float r1 = a01.y + __shfl_xor(a01.y, 32);
            const float r2 = a23.x + __shfl_xor(a23.x, 32);
            const float r3 = a23.y + __shfl_xor(a23.y, 32);

            if (lane < 32) {   // mean dims 4q..4q+3 -> As[w][4q..], bf16
                const float inv = deg ? 1.0f / (float)deg : 0.0f;
                uint2 o;
                o.x = pack2(r0 * inv, r1 * inv);
                o.y = pack2(r2 * inv, r3 * inv);
                const u32 byteM = ((u32)(w * 512 + q * 8)) ^ ((u32)(w & 7) << 4);
                *reinterpret_cast<uint2*>(reinterpret_cast<char*>(As) + byteM) = o;
            }
        }
        __syncthreads();   // As (mean + x halves) ready

        // ---- MFMA: this wave's col-tile x its K-half (4 x K32 steps) ----
        f32x4 acc = {0.f, 0.f, 0.f, 0.f};
        {
            const int kbase = kh * 128;
            const u32 ab0 = ((u32)(m16 * 512 + (kbase +  0 + kg * 8) * 2)) ^ ((u32)(m16 & 7) << 4);
            const u32 ab1 = ((u32)(m16 * 512 + (kbase + 32 + kg * 8) * 2)) ^ ((u32)(m16 & 7) << 4);
            const u32 ab2 = ((u32)(m16 * 512 + (kbase + 64 + kg * 8) * 2)) ^ ((u32)(m16 & 7) << 4);
            const u32 ab3 = ((u32)(m16 * 512 + (kbase + 96 + kg * 8) * 2)) ^ ((u32)(m16 & 7) << 4);
            const short8 af0 = *reinterpret_cast<const short8*>(reinterpret_cast<const char*>(As) + ab0);
            const short8 af1 = *reinterpret_cast<const short8*>(reinterpret_cast<const char*>(As) + ab1);
            const short8 af2 = *reinterpret_cast<const short8*>(reinterpret_cast<const char*>(As) + ab2);
            const short8 af3 = *reinterpret_cast<const short8*>(reinterpret_cast<const char*>(As) + ab3);
            acc = __builtin_amdgcn_mfma_f32_16x16x32_bf16(af0, wf0, acc, 0, 0, 0);
            acc = __builtin_amdgcn_mfma_f32_16x16x32_bf16(af1, wf1, acc, 0, 0, 0);
            acc = __builtin_amdgcn_mfma_f32_16x16x32_bf16(af2, wf2, acc, 0, 0, 0);
            acc = __builtin_amdgcn_mfma_f32_16x16x32_bf16(af3, wf3, acc, 0, 0, 0);
        }

        if (kh == 1) {     // upper K-half -> partial buffer
            #pragma unroll
            for (int i = 0; i < 4; i++)
                part[g & 1][kg * 4 + i][tc * 16 + m16] = acc[i];
        }
        __syncthreads();   // partials ready; As reads done

        if (kh == 0) {     // combine + bias + relu + guarded store
            #pragma unroll
            for (int i = 0; i < 4; i++) {
                const int grow = g * 16 + kg * 4 + i;
                if (grow < NPB) {
                    const float s = acc[i] + part[g & 1][kg * 4 + i][tc * 16 + m16] + bias;
                    out[(size_t)(row0 + grow) * D + tc * 16 + m16] = fmaxf(s, 0.f);
                }
            }
        }
    }
}

// ---------------------------------------------------------------------------
extern "C" void kernel_launch(void* const* d_in, const int* in_sizes, int n_in,
                              void* d_out, int out_size, void* d_ws, size_t ws_size,
                              hipStream_t stream) {
    const float* x  = (const float*)d_in[0];
    const int*   ei = (const int*)  d_in[1];
    const float* Wl = (const float*)d_in[2];
    const float* bl = (const float*)d_in[3];
    const float* Wr = (const float*)d_in[4];

    char* ws = (char*)d_ws;
    u32*   gcur   = (u32*)(ws + GCUR_OFF);
    u32*   region = (u32*)(ws + REG_OFF);
    u32*   xf8    = (u32*)(ws + XF8_OFF);
    uint4* Wb     = (uint4*)(ws + WB_OFF);
    float* out    = (float*)d_out;

    hipMemsetAsync(ws, 0, 4096, stream);    // gcur
    k_front <<<FRONTG, 512, 0, stream>>>(ei, x, Wl, Wr, gcur, region,
                                         (uint2*)xf8, Wb, xf8 + (size_t)NN * 32);
    k_aggemm<<<NB, 1024, 0, stream>>>(xf8, region, gcur, x, Wb, bl, out);
}

// Round 27
// 69.858 us; speedup vs baseline: 1.3794x; 1.0383x over previous
//
#include <hip/hip_runtime.h>
#include <hip/hip_bf16.h>

#define NN 50000
#define NE 1600000
#define D  128
#define NB   500            // coarse buckets (k_aggemm grid: ~2 blk/CU = 32 waves max)
#define NPB  100            // nodes per bucket
#define RCAP 4224           // region capacity per bucket (mean 3200 + 18 sigma)
#define NBB  512            // bucket-role blocks (run len 6.1 -> coalesced Phase C)
#define ECH  3125           // edges per bucket-role block (512 * 3125 = NE)
#define CASTB 1024          // cast-role blocks
#define FRONTG (NBB + CASTB + 8)
#define NGRP 7              // ceil(NPB/16) row groups per bucket
#define PSTR 132            // part[] stride: bank = (4*row+col)%32 -> 2-way max

typedef unsigned int u32;
typedef unsigned long long u64;
typedef unsigned short u16;
typedef __attribute__((ext_vector_type(8))) short short8;
typedef __attribute__((ext_vector_type(4))) float f32x4;
typedef __attribute__((ext_vector_type(2))) float f32x2;

// ws layout (bytes):
//   gcur u32[NB]        @ 0          (memset 0)
//   region u32[NB*RCAP] @ 4096       (8.45 MB)
//   xf8  fp8[(NN+1)*D]  @ 8452096    (6.4 MB)  e4m3; row NN = zeros
//   Wb   bf16[2*D*D]    @ 14852224   (64 KB)   Wl|Wr
#define GCUR_OFF 0
#define REG_OFF  4096
#define XF8_OFF  8452096
#define WB_OFF   14852224

__device__ __forceinline__ u32 pack2(float a, float b) {   // 2x f32 -> bf16 RNE
    u32 ua = __float_as_uint(a), ub = __float_as_uint(b);
    ua = (ua + 0x7FFFu + ((ua >> 16) & 1u)) >> 16;
    ub = (ub + 0x7FFFu + ((ub >> 16) & 1u)) >> 16;
    return ua | (ub << 16);
}

// ---------------------------------------------------------------------------
// Front mega-kernel: independent roles co-scheduled for overlap (round 26
// proven config: wave-shfl scan, no xb, Phase B LDS grouping + Phase C copy).
__global__ __launch_bounds__(512) void k_front(const int* __restrict__ ei,
                                               const float* __restrict__ x,
                                               const float* __restrict__ Wl,
                                               const float* __restrict__ Wr,
                                               u32* __restrict__ gcur,
                                               u32* __restrict__ region,
                                               uint2* __restrict__ xf8,
                                               uint4* __restrict__ Wb,
                                               u32* __restrict__ xzrow) {
    __shared__ u32 eL[ECH + 6];
    __shared__ u32 srt[ECH + 6];
    __shared__ u32 lh[512], sc[512], gb[512], lc[512];
    __shared__ u32 wsum[8];

    const int bid = blockIdx.x;
    const int t = threadIdx.x;

    if (bid >= NBB + CASTB) {
        // ---- prep role: 8 blocks x 512 = 4096 W slots ----
        const int s = (bid - NBB - CASTB) * 512 + t;
        const int mat = s >> 11;
        const int j   = (s >> 4) & 127;
        const int k8  = (s & 15) * 8;
        const float* src = (mat ? Wr : Wl) + (size_t)j * 128 + k8;
        const float4 a = reinterpret_cast<const float4*>(src)[0];
        const float4 b = reinterpret_cast<const float4*>(src)[1];
        uint4 o;
        o.x = pack2(a.x, a.y); o.y = pack2(a.z, a.w);
        o.z = pack2(b.x, b.y); o.w = pack2(b.z, b.w);
        Wb[s] = o;
        if (s < 32) xzrow[s] = 0u;     // fp8 0x00 == 0.0f
        return;
    }

    if (bid >= NBB) {
        // ---- cast role: x (f32) -> xf8 (fp8) only ----
        const int total = NN * D / 8;  // 800000
        for (int i = (bid - NBB) * 512 + t; i < total; i += CASTB * 512) {
            const float4 a = reinterpret_cast<const float4*>(x)[2 * i];
            const float4 b = reinterpret_cast<const float4*>(x)[2 * i + 1];
            uint2 o8;
            o8.x = (u32)__builtin_amdgcn_cvt_pk_fp8_f32(a.z, a.w,
                     __builtin_amdgcn_cvt_pk_fp8_f32(a.x, a.y, 0, false), true);
            o8.y = (u32)__builtin_amdgcn_cvt_pk_fp8_f32(b.z, b.w,
                     __builtin_amdgcn_cvt_pk_fp8_f32(b.x, b.y, 0, false), true);
            xf8[i] = o8;
        }
        return;
    }

    // ---- bucket role ----
    const int lane = t & 63;
    const u64 zmask = __ballot((u32)ei[2 * lane + 1] == 0u);
    const bool is64 = (zmask == ~0ull);

    const int e0 = bid * ECH;

    lh[t] = 0u; lc[t] = 0u;
    __syncthreads();

    // Phase A: load + histogram.  Entry = (bucket<<23)|(dst_local<<16)|src.
    for (int i = t; i < ECH; i += 512) {
        const int e = e0 + i;
        int src, dst;
        if (is64) { src = ei[2 * (size_t)e]; dst = ei[2 * (size_t)(NE + e)]; }
        else      { src = ei[e];             dst = ei[NE + e]; }
        const u32 b2 = (u32)dst / NPB;
        const u32 dl = (u32)dst - b2 * NPB;
        eL[i] = (b2 << 23) | (dl << 16) | (u32)src;
        atomicAdd(&lh[b2], 1u);
    }
    __syncthreads();

    // wave-shfl inclusive scan over 512 bins (2 barriers total)
    const u32 orig = lh[t];
    u32 v = orig;
    #pragma unroll
    for (int ofs = 1; ofs < 64; ofs <<= 1) {
        const u32 n = __shfl_up(v, ofs, 64);
        if (lane >= ofs) v += n;
    }
    if (lane == 63) wsum[t >> 6] = v;
    __syncthreads();
    u32 base = 0;
    #pragma unroll
    for (int ww = 0; ww < 8; ww++) base += (ww < (t >> 6)) ? wsum[ww] : 0u;
    v += base;
    sc[t] = v;                           // inclusive scan
    if (orig) gb[t] = atomicAdd(&gcur[t], orig);
    __syncthreads();

    // Phase B: group by bucket in LDS
    for (int i = t; i < ECH; i += 512) {
        const u32 e = eL[i];
        const u32 b2 = e >> 23;
        const u32 lp = atomicAdd(&lc[b2], 1u);
        srt[(sc[b2] - lh[b2]) + lp] = e;
    }
    __syncthreads();

    // Phase C: flat entry-parallel copy (run-coalesced)
    for (int i = t; i < ECH; i += 512) {
        const u32 e    = srt[i];
        const u32 b2   = e >> 23;
        const u32 run0 = sc[b2] - lh[b2];
        const u32 pos  = gb[b2] + ((u32)i - run0);
        if (pos < RCAP) region[(size_t)b2 * RCAP + pos] = e;
    }
}

// ---------------------------------------------------------------------------
// Fused aggregate + GEMM: one block (1024 thr, 16 waves) per bucket.
// Round 26 deltas: (1) guard-free main gather loop (full 16-edge chunks, no
// per-edge cndmask; one guarded tail iter), (2) shfl-scan for the 128-bin
// sort (2 barriers instead of 14). Everything else identical to 72.5 µs run.
#define GLOADU(J) \
    const u32 ev##J = srt[i + 2 * J + half]; \
    const u32 wv##J = xf8[(size_t)(ev##J & 0xFFFFu) * 32 + q];

#define GLOAD(J) \
    const int  i##J = i + 2 * J + half; \
    const u32 ev##J = srt[i##J]; \
    const u32 sr##J = (i##J < s1) ? (ev##J & 0xFFFFu) : (u32)NN; \
    const u32 wv##J = xf8[(size_t)sr##J * 32 + q];

#define GACC(J) { \
    const f32x2 lo = __builtin_amdgcn_cvt_pk_f32_fp8((int)wv##J, false); \
    const f32x2 hi = __builtin_amdgcn_cvt_pk_f32_fp8((int)wv##J, true); \
    a01 += lo; a23 += hi; }

__global__ __launch_bounds__(1024, 8) void k_aggemm(const u32* __restrict__ xf8,
                                                    const u32* __restrict__ region,
                                                    const u32* __restrict__ gcur,
                                                    const float* __restrict__ xf,
                                                    const uint4* __restrict__ Wb,
                                                    const float* __restrict__ bl,
                                                    float* __restrict__ out) {
    __shared__ u32 ent[RCAP];            // 16.9 KB staged entries (1 global pass)
    __shared__ u32 srt[RCAP + 16];       // 16.9 KB dst-sorted entries (+pad 16)
    __shared__ u32 hist[128], segs[128], cur[128];
    __shared__ u32 wsum2[2];
    __shared__ u16 As[16 * 256];         // 8 KB  [row-in-group][K=256] swizzled
    __shared__ float part[2][16][PSTR];  // 16.9 KB double-buffered K-partials

    const int t = threadIdx.x;
    const int b = blockIdx.x;

    if (t < 128) { hist[t] = 0u; cur[t] = 0u; }
    __syncthreads();

    u32 cnt = gcur[b];
    if (cnt > RCAP) cnt = RCAP;
    const u32* reg = region + (size_t)b * RCAP;

    // pass 1: stage + histogram (single global read)
    for (int i = t; i < (int)cnt; i += 1024) {
        const u32 e = reg[i];
        ent[i] = e;
        atomicAdd(&hist[(e >> 16) & 0x7Fu], 1u);
    }
    __syncthreads();

    // shfl inclusive scan of 128 bins (threads 0..127, 2 barriers)
    {
        u32 v = 0u;
        if (t < 128) {
            v = hist[t];
            #pragma unroll
            for (int ofs = 1; ofs < 64; ofs <<= 1) {
                const u32 n = __shfl_up(v, ofs, 64);
                if ((t & 63) >= ofs) v += n;
            }
            if ((t & 63) == 63) wsum2[t >> 6] = v;
        }
        __syncthreads();
        if (t < 128) {
            if (t >= 64) v += wsum2[0];
            segs[t] = v;
        }
    }
    __syncthreads();

    // pass 2: scatter into dst-sorted LDS order (from ent, no global read)
    for (int i = t; i < (int)cnt; i += 1024) {
        const u32 e = ent[i];
        const u32 dl = (e >> 16) & 0x7Fu;
        const u32 p = (segs[dl] - hist[dl]) + atomicAdd(&cur[dl], 1u);
        srt[p] = e;
    }
    if (t < 16) srt[cnt + t] = (u32)NN;  // pad (tail reads select-guarded)
    __syncthreads();

    // ---- per-wave identities ----
    const int w    = t >> 6;        // wave 0..15
    const int lane = t & 63;
    const int half = lane >> 5;
    const u32 q    = (u32)(lane & 31);
    const int m16  = lane & 15;
    const int kg   = lane >> 4;     // 0..3
    const int tc   = w & 7;         // col-tile (16 cols)
    const int kh   = w >> 3;        // K-half: 0 = mean@Wl, 1 = x@Wr
    const int row0 = b * NPB;

    // W fragments: 4 x short8 = 16 VGPRs, loaded once (L2-hot).
    const char* wbb = reinterpret_cast<const char*>(Wb) + kh * 32768
                    + (size_t)(tc * 16 + m16) * 256 + kg * 16;
    const short8 wf0 = *reinterpret_cast<const short8*>(wbb);
    const short8 wf1 = *reinterpret_cast<const short8*>(wbb + 64);
    const short8 wf2 = *reinterpret_cast<const short8*>(wbb + 128);
    const short8 wf3 = *reinterpret_cast<const short8*>(wbb + 192);
    const float bias = bl[tc * 16 + m16];

    // staging ids for the x-half (threads 0..255)
    const int sm   = t >> 4;        // row-in-group 0..15 (t<256)
    const int slot = t & 15;
    const u32 byteX = ((u32)(sm * 512 + (128 + slot * 8) * 2)) ^ ((u32)(sm & 7) << 4);

    for (int g = 0; g < NGRP; ++g) {
        // ---- stage x-half rows from f32 x (issue early; hidden by gather) ----
        if (t < 256) {
            const int grow = g * 16 + sm;
            uint4 o = {0u, 0u, 0u, 0u};
            if (grow < NPB) {
                const float* srcx = xf + (size_t)(row0 + grow) * D + slot * 8;
                const float4 a = reinterpret_cast<const float4*>(srcx)[0];
                const float4 bb = reinterpret_cast<const float4*>(srcx)[1];
                o.x = pack2(a.x, a.y);  o.y = pack2(a.z, a.w);
                o.z = pack2(bb.x, bb.y); o.w = pack2(bb.z, bb.w);
            }
            *reinterpret_cast<uint4*>(reinterpret_cast<char*>(As) + byteX) = o;
        }

        // ---- gather this wave's row: r = 16g + w ----
        const int r = g * 16 + w;
        if (r < NPB) {
            const int deg = (int)hist[r];
            const int s1  = (int)segs[r];
            const int s0  = s1 - deg;
            const int sfull = s0 + (deg & ~15);   // end of guard-free chunks

            f32x2 a01 = {0.f, 0.f}, a23 = {0.f, 0.f};
            int i = s0;
            for (; i < sfull; i += 16) {          // guard-free main loop
                GLOADU(0) GLOADU(1) GLOADU(2) GLOADU(3)
                GLOADU(4) GLOADU(5) GLOADU(6) GLOADU(7)
                GACC(0) GACC(1) GACC(2) GACC(3)
                GACC(4) GACC(5) GACC(6) GACC(7)
            }
            if (i < s1) {                          // one guarded tail iter
                GLOAD(0) GLOAD(1) GLOAD(2) GLOAD(3)
                GLOAD(4) GLOAD(5) GLOAD(6) GLOAD(7)
                GACC(0) GACC(1) GACC(2) GACC(3)
                GACC(4) GACC(5) GACC(6) GACC(7)
            }

            const float r0 = a01.x + __shfl_xor(a01.x, 32);
            const float r1 = a01.y + __shfl_xor(a01.y, 32);
            const float r2 = a23.x + __shfl_xor(a23.x, 32);
            const float r3 = a23.y + __shfl_xor(a23.y, 32);

            if (lane < 32) {   // mean dims 4q..4q+3 -> As[w][4q..], bf16
                const float inv = deg ? 1.0f / (float)deg : 0.0f;
                uint2 o;
                o.x = pack2(r0 * inv, r1 * inv);
                o.y = pack2(r2 * inv, r3 * inv);
                const u32 byteM = ((u32)(w * 512 + q * 8)) ^ ((u32)(w & 7) << 4);
                *reinterpret_cast<uint2*>(reinterpret_cast<char*>(As) + byteM) = o;
            }
        }
        __syncthreads();   // As (mean + x halves) ready

        // ---- MFMA: this wave's col-tile x its K-half (4 x K32 steps) ----
        f32x4 acc = {0.f, 0.f, 0.f, 0.f};
        {
            const int kbase = kh * 128;
            const u32 ab0 = ((u32)(m16 * 512 + (kbase +  0 + kg * 8) * 2)) ^ ((u32)(m16 & 7) << 4);
            const u32 ab1 = ((u32)(m16 * 512 + (kbase + 32 + kg * 8) * 2)) ^ ((u32)(m16 & 7) << 4);
            const u32 ab2 = ((u32)(m16 * 512 + (kbase + 64 + kg * 8) * 2)) ^ ((u32)(m16 & 7) << 4);
            const u32 ab3 = ((u32)(m16 * 512 + (kbase + 96 + kg * 8) * 2)) ^ ((u32)(m16 & 7) << 4);
            const short8 af0 = *reinterpret_cast<const short8*>(reinterpret_cast<const char*>(As) + ab0);
            const short8 af1 = *reinterpret_cast<const short8*>(reinterpret_cast<const char*>(As) + ab1);
            const short8 af2 = *reinterpret_cast<const short8*>(reinterpret_cast<const char*>(As) + ab2);
            const short8 af3 = *reinterpret_cast<const short8*>(reinterpret_cast<const char*>(As) + ab3);
            acc = __builtin_amdgcn_mfma_f32_16x16x32_bf16(af0, wf0, acc, 0, 0, 0);
            acc = __builtin_amdgcn_mfma_f32_16x16x32_bf16(af1, wf1, acc, 0, 0, 0);
            acc = __builtin_amdgcn_mfma_f32_16x16x32_bf16(af2, wf2, acc, 0, 0, 0);
            acc = __builtin_amdgcn_mfma_f32_16x16x32_bf16(af3, wf3, acc, 0, 0, 0);
        }

        if (kh == 1) {     // upper K-half -> partial buffer
            #pragma unroll
            for (int i = 0; i < 4; i++)
                part[g & 1][kg * 4 + i][tc * 16 + m16] = acc[i];
        }
        __syncthreads();   // partials ready; As reads done

        if (kh == 0) {     // combine + bias + relu + guarded store
            #pragma unroll
            for (int i = 0; i < 4; i++) {
                const int grow = g * 16 + kg * 4 + i;
                if (grow < NPB) {
                    const float s = acc[i] + part[g & 1][kg * 4 + i][tc * 16 + m16] + bias;
                    out[(size_t)(row0 + grow) * D + tc * 16 + m16] = fmaxf(s, 0.f);
                }
            }
        }
    }
}

// ---------------------------------------------------------------------------
extern "C" void kernel_launch(void* const* d_in, const int* in_sizes, int n_in,
                              void* d_out, int out_size, void* d_ws, size_t ws_size,
                              hipStream_t stream) {
    const float* x  = (const float*)d_in[0];
    const int*   ei = (const int*)  d_in[1];
    const float* Wl = (const float*)d_in[2];
    const float* bl = (const float*)d_in[3];
    const float* Wr = (const float*)d_in[4];

    char* ws = (char*)d_ws;
    u32*   gcur   = (u32*)(ws + GCUR_OFF);
    u32*   region = (u32*)(ws + REG_OFF);
    u32*   xf8    = (u32*)(ws + XF8_OFF);
    uint4* Wb     = (uint4*)(ws + WB_OFF);
    float* out    = (float*)d_out;

    hipMemsetAsync(ws, 0, 4096, stream);    // gcur
    k_front <<<FRONTG, 512, 0, stream>>>(ei, x, Wl, Wr, gcur, region,
                                         (uint2*)xf8, Wb, xf8 + (size_t)NN * 32);
    k_aggemm<<<NB, 1024, 0, stream>>>(xf8, region, gcur, x, Wb, bl, out);
}

// Round 28
// 69.119 us; speedup vs baseline: 1.3942x; 1.0107x over previous
//
#include <hip/hip_runtime.h>
#include <hip/hip_bf16.h>

#define NN 50000
#define NE 1600000
#define D  128
#define NB   500            // coarse buckets (k_aggemm grid: ~2 blk/CU = 32 waves max)
#define NPB  100            // nodes per bucket
#define RCAP 4224           // region capacity per bucket (mean 3200 + 18 sigma)
#define NBB  512            // bucket-role blocks (run len 6.1 -> coalesced Phase C)
#define ECH  3125           // edges per bucket-role block (512 * 3125 = NE)
#define CASTB 1024          // cast-role blocks
#define FRONTG (NBB + CASTB + 8)
#define NGRP 7              // ceil(NPB/16) row groups per bucket
#define PSTR 132            // part[] stride: bank = (4*row+col)%32 -> 2-way max

typedef unsigned int u32;
typedef unsigned long long u64;
typedef unsigned short u16;
typedef __attribute__((ext_vector_type(8))) short short8;
typedef __attribute__((ext_vector_type(4))) float f32x4;
typedef __attribute__((ext_vector_type(2))) float f32x2;

// ws layout (bytes):
//   gcur u32[NB]        @ 0          (memset 0)
//   region u32[NB*RCAP] @ 4096       (8.45 MB)
//   xf8  fp8[(NN+1)*D]  @ 8452096    (6.4 MB)  e4m3; row NN = zeros
//   Wb   bf16[2*D*D]    @ 14852224   (64 KB)   Wl|Wr
#define GCUR_OFF 0
#define REG_OFF  4096
#define XF8_OFF  8452096
#define WB_OFF   14852224

__device__ __forceinline__ u32 pack2(float a, float b) {   // 2x f32 -> bf16 RNE
    u32 ua = __float_as_uint(a), ub = __float_as_uint(b);
    ua = (ua + 0x7FFFu + ((ua >> 16) & 1u)) >> 16;
    ub = (ub + 0x7FFFu + ((ub >> 16) & 1u)) >> 16;
    return ua | (ub << 16);
}

// ---------------------------------------------------------------------------
// Front mega-kernel: independent roles co-scheduled for overlap.
// Round 27: Phase A's atomic return IS the within-run rank -> Phase B
// scatters with ZERO atomics (lc[] deleted; lpA u16 side array).
__global__ __launch_bounds__(512) void k_front(const int* __restrict__ ei,
                                               const float* __restrict__ x,
                                               const float* __restrict__ Wl,
                                               const float* __restrict__ Wr,
                                               u32* __restrict__ gcur,
                                               u32* __restrict__ region,
                                               uint2* __restrict__ xf8,
                                               uint4* __restrict__ Wb,
                                               u32* __restrict__ xzrow) {
    __shared__ u32 eL[ECH + 6];
    __shared__ u16 lpA[ECH + 6];
    __shared__ u32 srt[ECH + 6];
    __shared__ u32 lh[512], sc[512], gb[512];
    __shared__ u32 wsum[8];

    const int bid = blockIdx.x;
    const int t = threadIdx.x;

    if (bid >= NBB + CASTB) {
        // ---- prep role: 8 blocks x 512 = 4096 W slots ----
        const int s = (bid - NBB - CASTB) * 512 + t;
        const int mat = s >> 11;
        const int j   = (s >> 4) & 127;
        const int k8  = (s & 15) * 8;
        const float* src = (mat ? Wr : Wl) + (size_t)j * 128 + k8;
        const float4 a = reinterpret_cast<const float4*>(src)[0];
        const float4 b = reinterpret_cast<const float4*>(src)[1];
        uint4 o;
        o.x = pack2(a.x, a.y); o.y = pack2(a.z, a.w);
        o.z = pack2(b.x, b.y); o.w = pack2(b.z, b.w);
        Wb[s] = o;
        if (s < 32) xzrow[s] = 0u;     // fp8 0x00 == 0.0f
        return;
    }

    if (bid >= NBB) {
        // ---- cast role: x (f32) -> xf8 (fp8) only ----
        const int total = NN * D / 8;  // 800000
        for (int i = (bid - NBB) * 512 + t; i < total; i += CASTB * 512) {
            const float4 a = reinterpret_cast<const float4*>(x)[2 * i];
            const float4 b = reinterpret_cast<const float4*>(x)[2 * i + 1];
            uint2 o8;
            o8.x = (u32)__builtin_amdgcn_cvt_pk_fp8_f32(a.z, a.w,
                     __builtin_amdgcn_cvt_pk_fp8_f32(a.x, a.y, 0, false), true);
            o8.y = (u32)__builtin_amdgcn_cvt_pk_fp8_f32(b.z, b.w,
                     __builtin_amdgcn_cvt_pk_fp8_f32(b.x, b.y, 0, false), true);
            xf8[i] = o8;
        }
        return;
    }

    // ---- bucket role ----
    const int lane = t & 63;
    const u64 zmask = __ballot((u32)ei[2 * lane + 1] == 0u);
    const bool is64 = (zmask == ~0ull);

    const int e0 = bid * ECH;

    lh[t] = 0u;
    __syncthreads();

    // Phase A: load + histogram; atomic RETURN = within-run rank (stored).
    // Entry = (bucket<<23)|(dst_local<<16)|src.
    for (int i = t; i < ECH; i += 512) {
        const int e = e0 + i;
        int src, dst;
        if (is64) { src = ei[2 * (size_t)e]; dst = ei[2 * (size_t)(NE + e)]; }
        else      { src = ei[e];             dst = ei[NE + e]; }
        const u32 b2 = (u32)dst / NPB;
        const u32 dl = (u32)dst - b2 * NPB;
        eL[i] = (b2 << 23) | (dl << 16) | (u32)src;
        lpA[i] = (u16)atomicAdd(&lh[b2], 1u);
    }
    __syncthreads();

    // wave-shfl inclusive scan over 512 bins (2 barriers total)
    const u32 orig = lh[t];
    u32 v = orig;
    #pragma unroll
    for (int ofs = 1; ofs < 64; ofs <<= 1) {
        const u32 n = __shfl_up(v, ofs, 64);
        if (lane >= ofs) v += n;
    }
    if (lane == 63) wsum[t >> 6] = v;
    __syncthreads();
    u32 base = 0;
    #pragma unroll
    for (int ww = 0; ww < 8; ww++) base += (ww < (t >> 6)) ? wsum[ww] : 0u;
    v += base;
    sc[t] = v;                           // inclusive scan
    if (orig) gb[t] = atomicAdd(&gcur[t], orig);
    __syncthreads();

    // Phase B: group by bucket in LDS — ZERO atomics (rank precomputed)
    for (int i = t; i < ECH; i += 512) {
        const u32 e = eL[i];
        const u32 b2 = e >> 23;
        srt[(sc[b2] - lh[b2]) + (u32)lpA[i]] = e;
    }
    __syncthreads();

    // Phase C: flat entry-parallel copy (run-coalesced)
    for (int i = t; i < ECH; i += 512) {
        const u32 e    = srt[i];
        const u32 b2   = e >> 23;
        const u32 run0 = sc[b2] - lh[b2];
        const u32 pos  = gb[b2] + ((u32)i - run0);
        if (pos < RCAP) region[(size_t)b2 * RCAP + pos] = e;
    }
}

// ---------------------------------------------------------------------------
// Fused aggregate + GEMM: one block (1024 thr, 16 waves) per bucket.
// Round 27: pass-1 atomic return = rank (rnk u16) -> pass-2 scatter with
// ZERO atomics (cur[] deleted). Gather/MFMA identical to the 69.9 µs run.
#define GLOADU(J) \
    const u32 ev##J = srt[i + 2 * J + half]; \
    const u32 wv##J = xf8[(size_t)(ev##J & 0xFFFFu) * 32 + q];

#define GLOAD(J) \
    const int  i##J = i + 2 * J + half; \
    const u32 ev##J = srt[i##J]; \
    const u32 sr##J = (i##J < s1) ? (ev##J & 0xFFFFu) : (u32)NN; \
    const u32 wv##J = xf8[(size_t)sr##J * 32 + q];

#define GACC(J) { \
    const f32x2 lo = __builtin_amdgcn_cvt_pk_f32_fp8((int)wv##J, false); \
    const f32x2 hi = __builtin_amdgcn_cvt_pk_f32_fp8((int)wv##J, true); \
    a01 += lo; a23 += hi; }

__global__ __launch_bounds__(1024, 8) void k_aggemm(const u32* __restrict__ xf8,
                                                    const u32* __restrict__ region,
                                                    const u32* __restrict__ gcur,
                                                    const float* __restrict__ xf,
                                                    const uint4* __restrict__ Wb,
                                                    const float* __restrict__ bl,
                                                    float* __restrict__ out) {
    __shared__ u32 ent[RCAP];            // 16.9 KB staged entries (1 global pass)
    __shared__ u16 rnk[RCAP];            // 8.4 KB within-bin ranks
    __shared__ u32 srt[RCAP + 16];       // 16.9 KB dst-sorted entries (+pad 16)
    __shared__ u32 hist[128], segs[128];
    __shared__ u32 wsum2[2];
    __shared__ u16 As[16 * 256];         // 8 KB  [row-in-group][K=256] swizzled
    __shared__ float part[2][16][PSTR];  // 16.9 KB double-buffered K-partials

    const int t = threadIdx.x;
    const int b = blockIdx.x;

    if (t < 128) hist[t] = 0u;
    __syncthreads();

    u32 cnt = gcur[b];
    if (cnt > RCAP) cnt = RCAP;
    const u32* reg = region + (size_t)b * RCAP;

    // pass 1: stage + histogram; atomic RETURN = rank (stored)
    for (int i = t; i < (int)cnt; i += 1024) {
        const u32 e = reg[i];
        ent[i] = e;
        rnk[i] = (u16)atomicAdd(&hist[(e >> 16) & 0x7Fu], 1u);
    }
    __syncthreads();

    // shfl inclusive scan of 128 bins (threads 0..127, 2 barriers)
    {
        u32 v = 0u;
        if (t < 128) {
            v = hist[t];
            #pragma unroll
            for (int ofs = 1; ofs < 64; ofs <<= 1) {
                const u32 n = __shfl_up(v, ofs, 64);
                if ((t & 63) >= ofs) v += n;
            }
            if ((t & 63) == 63) wsum2[t >> 6] = v;
        }
        __syncthreads();
        if (t < 128) {
            if (t >= 64) v += wsum2[0];
            segs[t] = v;
        }
    }
    __syncthreads();

    // pass 2: scatter into dst-sorted LDS order — ZERO atomics
    for (int i = t; i < (int)cnt; i += 1024) {
        const u32 e = ent[i];
        const u32 dl = (e >> 16) & 0x7Fu;
        srt[(segs[dl] - hist[dl]) + (u32)rnk[i]] = e;
    }
    if (t < 16) srt[cnt + t] = (u32)NN;  // pad (tail reads select-guarded)
    __syncthreads();

    // ---- per-wave identities ----
    const int w    = t >> 6;        // wave 0..15
    const int lane = t & 63;
    const int half = lane >> 5;
    const u32 q    = (u32)(lane & 31);
    const int m16  = lane & 15;
    const int kg   = lane >> 4;     // 0..3
    const int tc   = w & 7;         // col-tile (16 cols)
    const int kh   = w >> 3;        // K-half: 0 = mean@Wl, 1 = x@Wr
    const int row0 = b * NPB;

    // W fragments: 4 x short8 = 16 VGPRs, loaded once (L2-hot).
    const char* wbb = reinterpret_cast<const char*>(Wb) + kh * 32768
                    + (size_t)(tc * 16 + m16) * 256 + kg * 16;
    const short8 wf0 = *reinterpret_cast<const short8*>(wbb);
    const short8 wf1 = *reinterpret_cast<const short8*>(wbb + 64);
    const short8 wf2 = *reinterpret_cast<const short8*>(wbb + 128);
    const short8 wf3 = *reinterpret_cast<const short8*>(wbb + 192);
    const float bias = bl[tc * 16 + m16];

    // staging ids for the x-half (threads 0..255)
    const int sm   = t >> 4;        // row-in-group 0..15 (t<256)
    const int slot = t & 15;
    const u32 byteX = ((u32)(sm * 512 + (128 + slot * 8) * 2)) ^ ((u32)(sm & 7) << 4);

    for (int g = 0; g < NGRP; ++g) {
        // ---- stage x-half rows from f32 x (issue early; hidden by gather) ----
        if (t < 256) {
            const int grow = g * 16 + sm;
            uint4 o = {0u, 0u, 0u, 0u};
            if (grow < NPB) {
                const float* srcx = xf + (size_t)(row0 + grow) * D + slot * 8;
                const float4 a = reinterpret_cast<const float4*>(srcx)[0];
                const float4 bb = reinterpret_cast<const float4*>(srcx)[1];
                o.x = pack2(a.x, a.y);  o.y = pack2(a.z, a.w);
                o.z = pack2(bb.x, bb.y); o.w = pack2(bb.z, bb.w);
            }
            *reinterpret_cast<uint4*>(reinterpret_cast<char*>(As) + byteX) = o;
        }

        // ---- gather this wave's row: r = 16g + w ----
        const int r = g * 16 + w;
        if (r < NPB) {
            const int deg = (int)hist[r];
            const int s1  = (int)segs[r];
            const int s0  = s1 - deg;
            const int sfull = s0 + (deg & ~15);   // end of guard-free chunks

            f32x2 a01 = {0.f, 0.f}, a23 = {0.f, 0.f};
            int i = s0;
            for (; i < sfull; i += 16) {          // guard-free main loop
                GLOADU(0) GLOADU(1) GLOADU(2) GLOADU(3)
                GLOADU(4) GLOADU(5) GLOADU(6) GLOADU(7)
                GACC(0) GACC(1) GACC(2) GACC(3)
                GACC(4) GACC(5) GACC(6) GACC(7)
            }
            if (i < s1) {                          // one guarded tail iter
                GLOAD(0) GLOAD(1) GLOAD(2) GLOAD(3)
                GLOAD(4) GLOAD(5) GLOAD(6) GLOAD(7)
                GACC(0) GACC(1) GACC(2) GACC(3)
                GACC(4) GACC(5) GACC(6) GACC(7)
            }

            const float r0 = a01.x + __shfl_xor(a01.x, 32);
            const float r1 = a01.y + __shfl_xor(a01.y, 32);
            const float r2 = a23.x + __shfl_xor(a23.x, 32);
            const float r3 = a23.y + __shfl_xor(a23.y, 32);

            if (lane < 32) {   // mean dims 4q..4q+3 -> As[w][4q..], bf16
                const float inv = deg ? 1.0f / (float)deg : 0.0f;
                uint2 o;
                o.x = pack2(r0 * inv, r1 * inv);
                o.y = pack2(r2 * inv, r3 * inv);
                const u32 byteM = ((u32)(w * 512 + q * 8)) ^ ((u32)(w & 7) << 4);
                *reinterpret_cast<uint2*>(reinterpret_cast<char*>(As) + byteM) = o;
            }
        }
        __syncthreads();   // As (mean + x halves) ready

        // ---- MFMA: this wave's col-tile x its K-half (4 x K32 steps) ----
        f32x4 acc = {0.f, 0.f, 0.f, 0.f};
        {
            const int kbase = kh * 128;
            const u32 ab0 = ((u32)(m16 * 512 + (kbase +  0 + kg * 8) * 2)) ^ ((u32)(m16 & 7) << 4);
            const u32 ab1 = ((u32)(m16 * 512 + (kbase + 32 + kg * 8) * 2)) ^ ((u32)(m16 & 7) << 4);
            const u32 ab2 = ((u32)(m16 * 512 + (kbase + 64 + kg * 8) * 2)) ^ ((u32)(m16 & 7) << 4);
            const u32 ab3 = ((u32)(m16 * 512 + (kbase + 96 + kg * 8) * 2)) ^ ((u32)(m16 & 7) << 4);
            const short8 af0 = *reinterpret_cast<const short8*>(reinterpret_cast<const char*>(As) + ab0);
            const short8 af1 = *reinterpret_cast<const short8*>(reinterpret_cast<const char*>(As) + ab1);
            const short8 af2 = *reinterpret_cast<const short8*>(reinterpret_cast<const char*>(As) + ab2);
            const short8 af3 = *reinterpret_cast<const short8*>(reinterpret_cast<const char*>(As) + ab3);
            acc = __builtin_amdgcn_mfma_f32_16x16x32_bf16(af0, wf0, acc, 0, 0, 0);
            acc = __builtin_amdgcn_mfma_f32_16x16x32_bf16(af1, wf1, acc, 0, 0, 0);
            acc = __builtin_amdgcn_mfma_f32_16x16x32_bf16(af2, wf2, acc, 0, 0, 0);
            acc = __builtin_amdgcn_mfma_f32_16x16x32_bf16(af3, wf3, acc, 0, 0, 0);
        }

        if (kh == 1) {     // upper K-half -> partial buffer
            #pragma unroll
            for (int i = 0; i < 4; i++)
                part[g & 1][kg * 4 + i][tc * 16 + m16] = acc[i];
        }
        __syncthreads();   // partials ready; As reads done

        if (kh == 0) {     // combine + bias + relu + guarded store
            #pragma unroll
            for (int i = 0; i < 4; i++) {
                const int grow = g * 16 + kg * 4 + i;
                if (grow < NPB) {
                    const float s = acc[i] + part[g & 1][kg * 4 + i][tc * 16 + m16] + bias;
                    out[(size_t)(row0 + grow) * D + tc * 16 + m16] = fmaxf(s, 0.f);
                }
            }
        }
    }
}

// ---------------------------------------------------------------------------
extern "C" void kernel_launch(void* const* d_in, const int* in_sizes, int n_in,
                              void* d_out, int out_size, void* d_ws, size_t ws_size,
                              hipStream_t stream) {
    const float* x  = (const float*)d_in[0];
    const int*   ei = (const int*)  d_in[1];
    const float* Wl = (const float*)d_in[2];
    const float* bl = (const float*)d_in[3];
    const float* Wr = (const float*)d_in[4];

    char* ws = (char*)d_ws;
    u32*   gcur   = (u32*)(ws + GCUR_OFF);
    u32*   region = (u32*)(ws + REG_OFF);
    u32*   xf8    = (u32*)(ws + XF8_OFF);
    uint4* Wb     = (uint4*)(ws + WB_OFF);
    float* out    = (float*)d_out;

    hipMemsetAsync(ws, 0, 4096, stream);    // gcur
    k_front <<<FRONTG, 512, 0, stream>>>(ei, x, Wl, Wr, gcur, region,
                                         (uint2*)xf8, Wb, xf8 + (size_t)NN * 32);
    k_aggemm<<<NB, 1024, 0, stream>>>(xf8, region, gcur, x, Wb, bl, out);
}